// Round 6
// baseline (45.561 us; speedup 1.0000x reference)
//
#include <hip/hip_runtime.h>

// CGA (Cl(4,1)) sandwich transform: out = decode( grade1( M X ~M ) )
// fp32 in/out buffers (harness upcasts fp16), fp64 accumulation (hidden under
// memory), final values rounded through fp16 like the reference.
// Round 6: 4 elements per thread -> all global access is float4 (motor 16x,
// x 3x, out 3x), NO LDS, NO barriers (round 5 showed block barriers cost ~7us).

namespace cga {

constexpr int METRIC[5] = {1, 1, 1, 1, -1};
constexpr int MB[16] = {0b00000, 0b00011, 0b00101, 0b01001, 0b10001, 0b00110, 0b01010, 0b10010,
                        0b01100, 0b10100, 0b11000, 0b01111, 0b10111, 0b11011, 0b11101, 0b11110};
constexpr int PB[5] = {0b00001, 0b00010, 0b00100, 0b01000, 0b10000};

constexpr int pc(int x) { int c = 0; while (x) { c += x & 1; x >>= 1; } return c; }

constexpr int gp_sign(int a, int b) {
    int s = 0;
    int aa = a >> 1;
    while (aa) { s += pc(aa & b); aa >>= 1; }
    int sign = (s & 1) ? -1 : 1;
    int common = a & b;
    for (int bit = 0; bit < 5; ++bit)
        if ((common >> bit) & 1) sign *= METRIC[bit];
    return sign;
}

constexpr int rev_sign(int blade) {
    int g = pc(blade);
    return ((g * (g - 1) / 2) & 1) ? -1 : 1;
}

struct Folded {
    signed char   sq_s[5][16];     // j==o square-term signs
    unsigned char pr_i[5][5][8];   // j!=o pair terms (i<k), sign in pr_s (2 folded into p)
    unsigned char pr_k[5][5][8];
    signed char   pr_s[5][5][8];
    int           pr_n[5][5];
};

constexpr Folded build() {
    signed char s[5][5][16] = {};
    unsigned char kk[5][5][16] = {};
    for (int o = 0; o < 5; ++o)
        for (int j = 0; j < 5; ++j)
            for (int i = 0; i < 16; ++i) {
                int mb = MB[i], pb = PB[j];
                int s1 = gp_sign(mb, pb);
                int ab = mb ^ pb;
                int nb = ab ^ PB[o];
                int q = 0;
                for (int c = 0; c < 16; ++c)
                    if (MB[c] == nb) q = c;
                kk[o][j][i] = (unsigned char)q;
                s[o][j][i] = (signed char)(s1 * gp_sign(ab, nb) * rev_sign(nb));
            }
    Folded f{};
    for (int o = 0; o < 5; ++o)
        for (int i = 0; i < 16; ++i)
            f.sq_s[o][i] = s[o][o][i];
    for (int o = 0; o < 5; ++o)
        for (int j = 0; j < 5; ++j) {
            if (j == o) { f.pr_n[o][j] = 0; continue; }
            int n = 0;
            for (int i = 0; i < 16; ++i) {
                int k = kk[o][j][i];
                if (i < k) {
                    int w = s[o][j][i] + s[o][j][k];
                    if (w != 0) {
                        f.pr_i[o][j][n] = (unsigned char)i;
                        f.pr_k[o][j][n] = (unsigned char)k;
                        f.pr_s[o][j][n] = (signed char)(w / 2);
                        ++n;
                    }
                }
            }
            f.pr_n[o][j] = n;
        }
    return f;
}

}  // namespace cga

__device__ constexpr cga::Folded FT = cga::build();

typedef float __attribute__((ext_vector_type(4))) f4v;

__global__ void __launch_bounds__(256) cga_sandwich_kernel(
    const float* __restrict__ motor,
    const float* __restrict__ x,
    float* __restrict__ out,
    int B) {
    const int g = blockIdx.x * 256 + threadIdx.x;
    const size_t e0 = (size_t)g * 4;
    if (e0 >= (size_t)B) return;

    // ---- all loads up front, all float4, no barriers ----
    const f4v* mp = reinterpret_cast<const f4v*>(motor + e0 * 16);
    const f4v* xv = reinterpret_cast<const f4v*>(x + e0 * 3);
    f4v mq[16];
#pragma unroll
    for (int i = 0; i < 16; ++i) mq[i] = mp[i];
    f4v xq0 = xv[0], xq1 = xv[1], xq2 = xv[2];
    float xf[12];
#pragma unroll
    for (int i = 0; i < 4; ++i) {
        xf[i] = xq0[i];
        xf[4 + i] = xq1[i];
        xf[8 + i] = xq2[i];
    }

    float rf[12];
#pragma unroll
    for (int e = 0; e < 4; ++e) {
        double md[16];
#pragma unroll
        for (int i = 0; i < 16; ++i) md[i] = (double)mq[e * 4 + i / 4][i % 4];

        // ---- UPGC encode (fp32, like the reference) ----
        float x0 = xf[e * 3 + 0];
        float x1 = xf[e * 3 + 1];
        float x2 = xf[e * 3 + 2];
        float sq = 0.5f * (x0 * x0 + x1 * x1 + x2 * x2);
        double pd[5];
        pd[0] = (double)x0;
        pd[1] = (double)x1;
        pd[2] = (double)x2;
        pd[3] = (double)(sq - 0.5f);
        pd[4] = (double)(sq + 0.5f);
        double pd2[5];
#pragma unroll
        for (int j = 0; j < 5; ++j) pd2[j] = pd[j] + pd[j];

        // ---- sandwich grade-1 part, fp64 ----
        double t[5];
#pragma unroll
        for (int o = 0; o < 5; ++o) {
            double aq = 0.0;
#pragma unroll
            for (int i = 0; i < 16; ++i) {
                const double mi = (FT.sq_s[o][i] > 0) ? md[i] : -md[i];
                aq = fma(mi, md[i], aq);
            }
            double acc = aq * pd[o];
#pragma unroll
            for (int j = 0; j < 5; ++j) {
                if (j == o) continue;
#pragma unroll
                for (int n = 0; n < 8; ++n) {
                    if (n < FT.pr_n[o][j]) {
                        const double mi = (FT.pr_s[o][j][n] > 0) ? md[FT.pr_i[o][j][n]]
                                                                 : -md[FT.pr_i[o][j][n]];
                        acc = fma(mi * md[FT.pr_k[o][j][n]], pd2[j], acc);
                    }
                }
            }
            t[o] = acc;
        }

        // ---- decode + fp16 rounding (reference casts to float16) ----
        double inv = 1.0 / (t[4] - t[3]);
        rf[e * 3 + 0] = (float)(_Float16)(float)(t[0] * inv);
        rf[e * 3 + 1] = (float)(_Float16)(float)(t[1] * inv);
        rf[e * 3 + 2] = (float)(_Float16)(float)(t[2] * inv);
    }

    // ---- 3 float4 stores ----
    f4v* ov = reinterpret_cast<f4v*>(out + e0 * 3);
#pragma unroll
    for (int i = 0; i < 3; ++i) {
        f4v v;
#pragma unroll
        for (int j = 0; j < 4; ++j) v[j] = rf[i * 4 + j];
        ov[i] = v;
    }
}

extern "C" void kernel_launch(void* const* d_in, const int* in_sizes, int n_in,
                              void* d_out, int out_size, void* d_ws, size_t ws_size,
                              hipStream_t stream) {
    const float* motor = (const float*)d_in[0];
    const float* x     = (const float*)d_in[1];
    float* out         = (float*)d_out;
    int B = in_sizes[0] / 16;              // motor is (B,16); B = 2^21
    int threads = (B + 3) / 4;             // 4 elements per thread
    int blocks = (threads + 255) / 256;    // 2048 blocks
    hipLaunchKernelGGL(cga_sandwich_kernel, dim3(blocks), dim3(256), 0, stream,
                       motor, x, out, B);
}

// Round 7
// 32.287 us; speedup vs baseline: 1.4111x; 1.4111x over previous
//
#include <hip/hip_runtime.h>

// CGA (Cl(4,1)) sandwich transform: out = decode( grade1( M X ~M ) )
// Inputs arrive as float32 (harness upcasts the reference's fp16 arrays);
// output buffer is float32, values rounded through fp16 like the reference's
// final astype(float16). Sandwich tensor folded at compile time:
//   j==o  -> 16 square terms  (+-1 * m_i^2)
//   j!=o  -> <=8 pair terms   (+-2 * m_i * m_k), 2 folded into 2*p_j
// fp64 accumulation: ~270 FMAs/elem, fully hidden under the memory floor.
//
// BEST = round 3 (32.5 us, 5.68 TB/s effective = 90% of copy ceiling).
// Reverted here after rounds 4-6 proved LDS staging (-7us), nontemporal
// hints (-12us), and 4-elem/thread vectorization (-13us) all REGRESS:
// the free-running 1-elem/thread kernel at max occupancy wins.

namespace cga {

constexpr int METRIC[5] = {1, 1, 1, 1, -1};
constexpr int MB[16] = {0b00000, 0b00011, 0b00101, 0b01001, 0b10001, 0b00110, 0b01010, 0b10010,
                        0b01100, 0b10100, 0b11000, 0b01111, 0b10111, 0b11011, 0b11101, 0b11110};
constexpr int PB[5] = {0b00001, 0b00010, 0b00100, 0b01000, 0b10000};

constexpr int pc(int x) { int c = 0; while (x) { c += x & 1; x >>= 1; } return c; }

constexpr int gp_sign(int a, int b) {
    int s = 0;
    int aa = a >> 1;
    while (aa) { s += pc(aa & b); aa >>= 1; }
    int sign = (s & 1) ? -1 : 1;
    int common = a & b;
    for (int bit = 0; bit < 5; ++bit)
        if ((common >> bit) & 1) sign *= METRIC[bit];
    return sign;
}

constexpr int rev_sign(int blade) {
    int g = pc(blade);
    return ((g * (g - 1) / 2) & 1) ? -1 : 1;
}

struct Folded {
    signed char   sq_s[5][16];     // j==o square-term signs
    unsigned char pr_i[5][5][8];   // j!=o pair terms (i<k), weight sign in pr_s
    unsigned char pr_k[5][5][8];
    signed char   pr_s[5][5][8];
    int           pr_n[5][5];
};

constexpr Folded build() {
    signed char s[5][5][16] = {};
    unsigned char kk[5][5][16] = {};
    for (int o = 0; o < 5; ++o)
        for (int j = 0; j < 5; ++j)
            for (int i = 0; i < 16; ++i) {
                int mb = MB[i], pb = PB[j];
                int s1 = gp_sign(mb, pb);
                int ab = mb ^ pb;
                int nb = ab ^ PB[o];
                int q = 0;
                for (int c = 0; c < 16; ++c)
                    if (MB[c] == nb) q = c;
                kk[o][j][i] = (unsigned char)q;
                s[o][j][i] = (signed char)(s1 * gp_sign(ab, nb) * rev_sign(nb));
            }
    Folded f{};
    for (int o = 0; o < 5; ++o)
        for (int i = 0; i < 16; ++i)
            f.sq_s[o][i] = s[o][o][i];
    for (int o = 0; o < 5; ++o)
        for (int j = 0; j < 5; ++j) {
            if (j == o) { f.pr_n[o][j] = 0; continue; }
            int n = 0;
            for (int i = 0; i < 16; ++i) {
                int k = kk[o][j][i];
                if (i < k) {
                    int w = s[o][j][i] + s[o][j][k];
                    if (w != 0) {
                        f.pr_i[o][j][n] = (unsigned char)i;
                        f.pr_k[o][j][n] = (unsigned char)k;
                        f.pr_s[o][j][n] = (signed char)(w / 2);
                        ++n;
                    }
                }
            }
            f.pr_n[o][j] = n;
        }
    return f;
}

}  // namespace cga

__device__ constexpr cga::Folded FT = cga::build();

__global__ void __launch_bounds__(256) cga_sandwich_kernel(
    const float* __restrict__ motor,
    const float* __restrict__ x,
    float* __restrict__ out,
    int B) {
    int b = blockIdx.x * 256 + threadIdx.x;
    if (b >= B) return;

    // ---- motor row: 16 fp32 = 64 B, four 16B vector loads ----
    const float4* mp = reinterpret_cast<const float4*>(motor + (size_t)b * 16);
    float4 q0 = mp[0], q1 = mp[1], q2 = mp[2], q3 = mp[3];
    double md[16] = {q0.x, q0.y, q0.z, q0.w, q1.x, q1.y, q1.z, q1.w,
                     q2.x, q2.y, q2.z, q2.w, q3.x, q3.y, q3.z, q3.w};

    // ---- point + UPGC encode (fp32, like the reference) ----
    const float* xp = x + (size_t)b * 3;
    float x0 = xp[0], x1 = xp[1], x2 = xp[2];
    float sq = 0.5f * (x0 * x0 + x1 * x1 + x2 * x2);
    double pd[5];
    pd[0] = (double)x0;
    pd[1] = (double)x1;
    pd[2] = (double)x2;
    pd[3] = (double)(sq - 0.5f);
    pd[4] = (double)(sq + 0.5f);
    double pd2[5];
#pragma unroll
    for (int j = 0; j < 5; ++j) pd2[j] = pd[j] + pd[j];

    // ---- sandwich grade-1 part, fp64 ----
    double t[5];
#pragma unroll
    for (int o = 0; o < 5; ++o) {
        double aq = 0.0;
#pragma unroll
        for (int i = 0; i < 16; ++i) {
            const double mi = (FT.sq_s[o][i] > 0) ? md[i] : -md[i];
            aq = fma(mi, md[i], aq);
        }
        double acc = aq * pd[o];
#pragma unroll
        for (int j = 0; j < 5; ++j) {
            if (j == o) continue;
            double a = 0.0;
#pragma unroll
            for (int n = 0; n < 8; ++n) {
                if (n < FT.pr_n[o][j]) {
                    const double mi = (FT.pr_s[o][j][n] > 0) ? md[FT.pr_i[o][j][n]]
                                                             : -md[FT.pr_i[o][j][n]];
                    a = fma(mi, md[FT.pr_k[o][j][n]], a);
                }
            }
            acc = fma(a, pd2[j], acc);
        }
        t[o] = acc;
    }

    // ---- decode + fp16 rounding (reference casts to float16) ----
    double inv = 1.0 / (t[4] - t[3]);
    float r0 = (float)(_Float16)(float)(t[0] * inv);
    float r1 = (float)(_Float16)(float)(t[1] * inv);
    float r2 = (float)(_Float16)(float)(t[2] * inv);

    float* op = out + (size_t)b * 3;
    op[0] = r0;
    op[1] = r1;
    op[2] = r2;
}

extern "C" void kernel_launch(void* const* d_in, const int* in_sizes, int n_in,
                              void* d_out, int out_size, void* d_ws, size_t ws_size,
                              hipStream_t stream) {
    const float* motor = (const float*)d_in[0];
    const float* x     = (const float*)d_in[1];
    float* out         = (float*)d_out;
    int B = in_sizes[0] / 16;  // motor is (B,16)
    int blocks = (B + 255) / 256;
    hipLaunchKernelGGL(cga_sandwich_kernel, dim3(blocks), dim3(256), 0, stream,
                       motor, x, out, B);
}